// Round 6
// baseline (341.964 us; speedup 1.0000x reference)
//
#include <hip/hip_runtime.h>
#include <math.h>

// ---- Problem constants ----
#define B_    128
#define L_    512
#define H_    128
#define NPT_  1023
#define N_    (B_ * NPT_)     // 130944
#define NLEAF (B_ * L_)       // 65536
#define OUT_  128
#define VOCAB 32000

#define PADK  264             // 256+8 shorts: K=256 row stride (A and B tiles)
#define PADKL 136             // 128+8 shorts: K=128 row stride (leaf)

typedef unsigned short ushort_t;
typedef __attribute__((ext_vector_type(8))) __bf16 bf16x8;
typedef __attribute__((ext_vector_type(4))) float f32x4;

__device__ __forceinline__ float sigmoidf_(float x) {
    return 1.0f / (1.0f + __expf(-x));
}
__device__ __forceinline__ float tanhf_(float x) {
    return 1.0f - 2.0f / (__expf(2.0f * x) + 1.0f);
}
__device__ __forceinline__ ushort_t f2bf(float f) {
    unsigned u = __float_as_uint(f);
    return (ushort_t)((u + 0x7fffu + ((u >> 16) & 1u)) >> 16);
}
__device__ __forceinline__ float bf2f(ushort_t s) {
    return __uint_as_float(((unsigned)s) << 16);
}

// =====================================================================
// Prep A: weights -> bf16, transposed.
// =====================================================================
__global__ __launch_bounds__(256)
void prep_kernel(const float* __restrict__ W_iou,
                 const float* __restrict__ U_iou,
                 const float* __restrict__ U_f_w,
                 ushort_t* __restrict__ W_iouT,     // [384][128]
                 ushort_t* __restrict__ U_catT) {   // [640][256]
    int idx = blockIdx.x * 256 + threadIdx.x;
    if (idx < 640 * 256) {
        int n = idx >> 8, k = idx & 255;
        float v = (n < 384) ? U_iou[k * 384 + n] : U_f_w[k * 256 + (n - 384)];
        U_catT[idx] = f2bf(v);
    }
    if (idx < 384 * 128) {
        int n = idx >> 7, k = idx & 127;
        W_iouT[idx] = f2bf(W_iou[k * 384 + n]);
    }
}

// =====================================================================
// Prep B: emb -> bf16.
// =====================================================================
__global__ __launch_bounds__(256)
void prep_emb(const float* __restrict__ emb, ushort_t* __restrict__ embb) {
    int idx = (blockIdx.x * 256 + threadIdx.x) * 8;
    if (idx < VOCAB * H_) {
        f32x4 f0 = *(const f32x4*)(emb + idx);
        f32x4 f1 = *(const f32x4*)(emb + idx + 4);
        union { bf16x8 v; ushort_t e[8]; } p;
        p.e[0] = f2bf(f0[0]); p.e[1] = f2bf(f0[1]);
        p.e[2] = f2bf(f0[2]); p.e[3] = f2bf(f0[3]);
        p.e[4] = f2bf(f1[0]); p.e[5] = f2bf(f1[1]);
        p.e[6] = f2bf(f1[2]); p.e[7] = f2bf(f1[3]);
        *(bf16x8*)((ushort_t*)embb + idx) = p.v;
    }
}

// =====================================================================
// Leaf v2: B (W_iouT slice, 4 gate groups x 3 tiles) staged in LDS once
// per block; block loops over tiles_pb M-tiles of 128 leaves, A
// register-prefetched then staged in LDS. Wave w = gate group
// gg = blockIdx.y*4 + w over all 128 rows (8 M-subs, acc[8][3]=96 AGPR).
// =====================================================================
__global__ __launch_bounds__(256)
void leaf_mfma2(const int* __restrict__ label,
                const ushort_t* __restrict__ embb,  // [VOCAB][128] bf16
                const ushort_t* __restrict__ WT,    // [384][128] bf16
                const float* __restrict__ b_iou,
                ushort_t* __restrict__ h,
                float* __restrict__ c,
                int tiles_pb) {
    extern __shared__ ushort_t smem[];
    ushort_t* Bs = smem;                 // 192 rows x PADKL
    ushort_t* As = smem + 192 * PADKL;   // 128 rows x PADKL

    const int tid  = threadIdx.x;
    const int lane = tid & 63;
    const int wave = tid >> 6;
    const int li   = lane & 15;
    const int q    = lane >> 4;
    const int q8   = q << 3;
    const int cls  = blockIdx.y;                    // 0..1
    const int gg   = cls * 4 + wave;
    const int i0b  = blockIdx.x * tiles_pb * 128;

    // stage B: 192 rows (4 groups x 3 tiles x 16) of 128 shorts
    for (int ci = tid; ci < 192 * 16; ci += 256) {
        int r = ci >> 4, ch = ci & 15;
        int gp = r / 48, rr = r % 48;
        int t = rr >> 4, r16 = rr & 15;
        int grow = 16 * (cls * 4 + gp + 8 * t) + r16;
        *(f32x4*)(Bs + r * PADKL + ch * 8) = *(const f32x4*)(WT + (size_t)grow * 128 + ch * 8);
    }

    // prefetch A tile 0 (gather emb_bf16 rows via label)
    f32x4 pre[8];
    {
        int i0 = i0b;
        #pragma unroll
        for (int k = 0; k < 8; ++k) {
            int ci = k * 256 + tid;
            int r = ci >> 4, ch = ci & 15;
            int i = i0 + r, b = i >> 9, pos = i & 511;
            pre[k] = *(const f32x4*)(embb + (size_t)label[b * NPT_ + pos] * H_ + ch * 8);
        }
    }

    const int j = gg * 16 + li;
    const float bi = b_iou[j], bo = b_iou[128 + j], bu = b_iou[256 + j];

    for (int tt = 0; tt < tiles_pb; ++tt) {
        const int i0 = i0b + tt * 128;
        // store prefetched A into LDS
        #pragma unroll
        for (int k = 0; k < 8; ++k) {
            int ci = k * 256 + tid;
            int r = ci >> 4, ch = ci & 15;
            *(f32x4*)(As + r * PADKL + ch * 8) = pre[k];
        }
        __syncthreads();
        // prefetch next tile
        if (tt + 1 < tiles_pb) {
            int i0n = i0 + 128;
            #pragma unroll
            for (int k = 0; k < 8; ++k) {
                int ci = k * 256 + tid;
                int r = ci >> 4, ch = ci & 15;
                int i = i0n + r, b = i >> 9, pos = i & 511;
                pre[k] = *(const f32x4*)(embb + (size_t)label[b * NPT_ + pos] * H_ + ch * 8);
            }
        }

        f32x4 acc[8][3];
        #pragma unroll
        for (int s = 0; s < 8; ++s)
            #pragma unroll
            for (int t = 0; t < 3; ++t) acc[s][t] = (f32x4){0.f, 0.f, 0.f, 0.f};

        #pragma unroll
        for (int kt = 0; kt < 4; ++kt) {
            bf16x8 a[8];
            #pragma unroll
            for (int s = 0; s < 8; ++s)
                a[s] = *(const bf16x8*)(As + (s * 16 + li) * PADKL + kt * 32 + q8);
            #pragma unroll
            for (int t = 0; t < 3; ++t) {
                bf16x8 bf = *(const bf16x8*)(Bs + ((wave * 3 + t) * 16 + li) * PADKL + kt * 32 + q8);
                #pragma unroll
                for (int s = 0; s < 8; ++s)
                    acc[s][t] = __builtin_amdgcn_mfma_f32_16x16x32_bf16(a[s], bf, acc[s][t], 0, 0, 0);
            }
        }

        #pragma unroll
        for (int s = 0; s < 8; ++s) {
            #pragma unroll
            for (int r = 0; r < 4; ++r) {
                int m  = i0 + s * 16 + q * 4 + r;
                int b  = m >> 9, pos = m & 511;
                size_t gn = (size_t)(b * NPT_ + pos) * H_ + j;
                float iv = sigmoidf_(acc[s][0][r] + bi);
                float ov = sigmoidf_(acc[s][1][r] + bo);
                float uv = tanhf_(acc[s][2][r] + bu);
                float cv = iv * uv;
                float hv = ov * tanhf_(cv);
                c[gn] = cv;
                h[gn] = f2bf(hv);
            }
        }
        __syncthreads();    // all LDS reads done before next store
    }
}

// =====================================================================
// Level v2 (big levels): B (Ucat slice, 2 gate groups x 5 tiles) in LDS
// once per block; loop over tiles_pb M-tiles of 128 nodes with
// register-prefetched A (h_cat). Wave w: group gp=w>>1, M-half w&1
// (M=64/wave, acc[4][5]=80 AGPR).
// =====================================================================
__global__ __launch_bounds__(256)
void level_mfma2(const ushort_t* __restrict__ Ucat,  // [640][256] bf16
                 const float* __restrict__ b_iou,
                 const float* __restrict__ U_f_b,
                 ushort_t* __restrict__ h,
                 float* __restrict__ c,
                 int node_base, int child_base, int lc, int tiles_pb) {
    extern __shared__ ushort_t smem[];
    ushort_t* Bs = smem;                 // 160 rows x PADK
    ushort_t* As = smem + 160 * PADK;    // 128 rows x PADK

    const int tid  = threadIdx.x;
    const int lane = tid & 63;
    const int wave = tid >> 6;
    const int li   = lane & 15;
    const int q    = lane >> 4;
    const int q8   = q << 3;
    const int mask = (1 << lc) - 1;
    const int cls  = blockIdx.y;                    // 0..3
    const int gp   = wave >> 1;                     // group within block
    const int mh   = wave & 1;                      // M-half
    const int gg   = cls * 2 + gp;
    const int i0b  = blockIdx.x * tiles_pb * 128;

    // stage B: 160 rows (2 groups x 5 tiles x 16) of 256 shorts
    for (int ci = tid; ci < 160 * 32; ci += 256) {
        int r = ci >> 5, ch = ci & 31;
        int g2 = r / 80, rr = r % 80;
        int t = rr >> 4, r16 = rr & 15;
        int grow = 16 * (cls * 2 + g2 + 8 * t) + r16;
        *(f32x4*)(Bs + r * PADK + ch * 8) = *(const f32x4*)(Ucat + (size_t)grow * 256 + ch * 8);
    }

    // prefetch A tile 0: row r = [h[left] | h[right]]
    f32x4 pre[16];
    {
        int i0 = i0b;
        #pragma unroll
        for (int k = 0; k < 16; ++k) {
            int ci = k * 256 + tid;
            int r = ci >> 5, ch = ci & 31;
            int side = ch >> 4, cch = ch & 15;
            int i = i0 + r, b = i >> lc, pos = i & mask;
            int gc = b * NPT_ + child_base + 2 * pos + side;
            pre[k] = *(const f32x4*)(h + (size_t)gc * H_ + cch * 8);
        }
    }

    const int j = gg * 16 + li;
    const float bi  = b_iou[j], bo = b_iou[128 + j], bu = b_iou[256 + j];
    const float bfl = U_f_b[j], bfr = U_f_b[128 + j];

    for (int tt = 0; tt < tiles_pb; ++tt) {
        const int i0 = i0b + tt * 128;
        #pragma unroll
        for (int k = 0; k < 16; ++k) {
            int ci = k * 256 + tid;
            int r = ci >> 5, ch = ci & 31;
            *(f32x4*)(As + r * PADK + ch * 8) = pre[k];
        }
        __syncthreads();
        if (tt + 1 < tiles_pb) {
            int i0n = i0 + 128;
            #pragma unroll
            for (int k = 0; k < 16; ++k) {
                int ci = k * 256 + tid;
                int r = ci >> 5, ch = ci & 31;
                int side = ch >> 4, cch = ch & 15;
                int i = i0n + r, b = i >> lc, pos = i & mask;
                int gc = b * NPT_ + child_base + 2 * pos + side;
                pre[k] = *(const f32x4*)(h + (size_t)gc * H_ + cch * 8);
            }
        }

        f32x4 acc[4][5];
        #pragma unroll
        for (int s = 0; s < 4; ++s)
            #pragma unroll
            for (int t = 0; t < 5; ++t) acc[s][t] = (f32x4){0.f, 0.f, 0.f, 0.f};

        #pragma unroll
        for (int kt = 0; kt < 8; ++kt) {
            bf16x8 a[4];
            #pragma unroll
            for (int s = 0; s < 4; ++s)
                a[s] = *(const bf16x8*)(As + (mh * 64 + s * 16 + li) * PADK + kt * 32 + q8);
            #pragma unroll
            for (int t = 0; t < 5; ++t) {
                bf16x8 bf = *(const bf16x8*)(Bs + ((gp * 5 + t) * 16 + li) * PADK + kt * 32 + q8);
                #pragma unroll
                for (int s = 0; s < 4; ++s)
                    acc[s][t] = __builtin_amdgcn_mfma_f32_16x16x32_bf16(a[s], bf, acc[s][t], 0, 0, 0);
            }
        }

        #pragma unroll
        for (int s = 0; s < 4; ++s) {
            #pragma unroll
            for (int r = 0; r < 4; ++r) {
                int m   = i0 + mh * 64 + s * 16 + q * 4 + r;
                int b   = m >> lc, pos = m & mask;
                int gn  = b * NPT_ + node_base + pos;
                int gl  = b * NPT_ + child_base + 2 * pos;
                float iv = sigmoidf_(acc[s][0][r] + bi);
                float ov = sigmoidf_(acc[s][1][r] + bo);
                float uv = tanhf_(acc[s][2][r] + bu);
                float fl = sigmoidf_(acc[s][3][r] + bfl);
                float fr = sigmoidf_(acc[s][4][r] + bfr);
                float cv = iv * uv + fl * c[(size_t)gl * H_ + j]
                                   + fr * c[(size_t)(gl + 1) * H_ + j];
                float hv = ov * tanhf_(cv);
                c[(size_t)gn * H_ + j] = cv;
                h[(size_t)gn * H_ + j] = f2bf(hv);
            }
        }
        __syncthreads();
    }
}

// =====================================================================
// Level v1 (small levels, M<=1024): round-5 kernel, B from L2.
// =====================================================================
__global__ __launch_bounds__(256, 4)
void level_mfma(const ushort_t* __restrict__ Ucat,
                const float* __restrict__ b_iou,
                const float* __restrict__ U_f_b,
                ushort_t* __restrict__ h,
                float* __restrict__ c,
                int node_base, int child_base, int lc) {
    __shared__ ushort_t As[32 * PADK];
    const int tid  = threadIdx.x;
    const int lane = tid & 63;
    const int wave = tid >> 6;
    const int li   = lane & 15;
    const int q    = lane >> 4;
    const int q8   = q << 3;
    const int mask = (1 << lc) - 1;
    const int i0   = blockIdx.x * 32;
    const int gg   = blockIdx.y * 4 + wave;

    {
        int r   = tid >> 3;
        int seg = tid & 7;
        int s   = seg >> 2, cs = seg & 3;
        int i   = i0 + r;
        int b   = i >> lc, pos = i & mask;
        int gc  = b * NPT_ + child_base + 2 * pos + s;
        const ushort_t* src = h + (size_t)gc * H_ + cs * 32;
        ushort_t*       dst = As + r * PADK + s * 128 + cs * 32;
        #pragma unroll
        for (int u = 0; u < 4; ++u)
            *(f32x4*)(dst + u * 8) = *(const f32x4*)(src + u * 8);
    }
    __syncthreads();

    const ushort_t* bp[5];
    #pragma unroll
    for (int t = 0; t < 5; ++t)
        bp[t] = Ucat + (size_t)(16 * (gg + 8 * t) + li) * 256 + q8;

    f32x4 acc[2][5];
    #pragma unroll
    for (int s = 0; s < 2; ++s)
        #pragma unroll
        for (int t = 0; t < 5; ++t) acc[s][t] = (f32x4){0.f, 0.f, 0.f, 0.f};

    #pragma unroll
    for (int kt = 0; kt < 8; ++kt) {
        bf16x8 a0 = *(const bf16x8*)(As + (li) * PADK + kt * 32 + q8);
        bf16x8 a1 = *(const bf16x8*)(As + (16 + li) * PADK + kt * 32 + q8);
        #pragma unroll
        for (int t = 0; t < 5; ++t) {
            bf16x8 bf = *(const bf16x8*)(bp[t] + kt * 32);
            acc[0][t] = __builtin_amdgcn_mfma_f32_16x16x32_bf16(a0, bf, acc[0][t], 0, 0, 0);
            acc[1][t] = __builtin_amdgcn_mfma_f32_16x16x32_bf16(a1, bf, acc[1][t], 0, 0, 0);
        }
    }

    const int j = gg * 16 + li;
    const float bi  = b_iou[j], bo = b_iou[128 + j], bu = b_iou[256 + j];
    const float bfl = U_f_b[j], bfr = U_f_b[128 + j];
    #pragma unroll
    for (int sub = 0; sub < 2; ++sub) {
        #pragma unroll
        for (int r = 0; r < 4; ++r) {
            int m   = i0 + sub * 16 + q * 4 + r;
            int b   = m >> lc, pos = m & mask;
            int gn  = b * NPT_ + node_base + pos;
            int gl  = b * NPT_ + child_base + 2 * pos;
            float iv = sigmoidf_(acc[sub][0][r] + bi);
            float ov = sigmoidf_(acc[sub][1][r] + bo);
            float uv = tanhf_(acc[sub][2][r] + bu);
            float fl = sigmoidf_(acc[sub][3][r] + bfl);
            float fr = sigmoidf_(acc[sub][4][r] + bfr);
            float cv = iv * uv + fl * c[(size_t)gl * H_ + j]
                               + fr * c[(size_t)(gl + 1) * H_ + j];
            float hv = ov * tanhf_(cv);
            c[(size_t)gn * H_ + j] = cv;
            h[(size_t)gn * H_ + j] = f2bf(hv);
        }
    }
}

// =====================================================================
// Root: logits + log_softmax.
// =====================================================================
__global__ __launch_bounds__(128)
void root_kernel(const ushort_t* __restrict__ h,
                 const float* __restrict__ W_out,
                 const float* __restrict__ b_out,
                 float* __restrict__ out) {
    __shared__ float e[H_];
    __shared__ float red[128];
    const int j = threadIdx.x;
    const int b = blockIdx.x;
    const size_t g = (size_t)(b * NPT_ + (NPT_ - 1)) * H_;

    e[j] = bf2f(h[g + j]);
    __syncthreads();

    float acc = b_out[j];
    for (int k = 0; k < H_; ++k)
        acc += e[k] * W_out[k * OUT_ + j];

    red[j] = acc; __syncthreads();
    #pragma unroll
    for (int s = 64; s > 0; s >>= 1) {
        if (j < s) red[j] = fmaxf(red[j], red[j + s]);
        __syncthreads();
    }
    float mx = red[0]; __syncthreads();

    red[j] = expf(acc - mx); __syncthreads();
    #pragma unroll
    for (int s = 64; s > 0; s >>= 1) {
        if (j < s) red[j] += red[j + s];
        __syncthreads();
    }
    float lse = logf(red[0]);

    out[b * OUT_ + j] = acc - mx - lse;
}

// =====================================================================
extern "C" void kernel_launch(void* const* d_in, const int* in_sizes, int n_in,
                              void* d_out, int out_size, void* d_ws, size_t ws_size,
                              hipStream_t stream) {
    const int*   label = (const int*)d_in[0];
    const float* emb   = (const float*)d_in[1];
    const float* W_iou = (const float*)d_in[2];
    const float* U_iou = (const float*)d_in[3];
    const float* b_iou = (const float*)d_in[4];
    const float* U_f_w = (const float*)d_in[5];
    const float* U_f_b = (const float*)d_in[6];
    const float* W_out = (const float*)d_in[7];
    const float* b_out = (const float*)d_in[8];

    float*    c    = (float*)d_ws;
    ushort_t* h    = (ushort_t*)(c + (size_t)N_ * H_);
    ushort_t* Ucat = h + (size_t)N_ * H_;
    ushort_t* WT   = Ucat + 640 * 256;
    ushort_t* embb = WT + 384 * 128;

    prep_kernel<<<640, 256, 0, stream>>>(W_iou, U_iou, U_f_w, WT, Ucat);
    prep_emb<<<(VOCAB * H_ / 8 + 255) / 256, 256, 0, stream>>>(emb, embb);

    // leaf: 512 M-tiles, 128 stripes x 2 classes, 4 tiles/block
    {
        size_t lds = (size_t)(192 * PADKL + 128 * PADKL) * 2;   // 87 KB
        leaf_mfma2<<<dim3(128, 2), 256, lds, stream>>>(label, embb, WT, b_iou, h, c, 4);
    }

    int child = 0, node = 512, cnt = 256, lc = 8;
    for (int lvl = 0; lvl < 9; ++lvl) {
        int rows = B_ * cnt;
        if (rows >= 2048) {
            int tiles   = rows / 128;
            int stripes = tiles <= 64 ? tiles : 64;
            size_t lds  = (size_t)(160 * PADK + 128 * PADK) * 2;  // 152 KB
            level_mfma2<<<dim3(stripes, 4), 256, lds, stream>>>(
                Ucat, b_iou, U_f_b, h, c, node, child, lc, tiles / stripes);
        } else {
            level_mfma<<<dim3(rows / 32, 2), 256, 0, stream>>>(
                Ucat, b_iou, U_f_b, h, c, node, child, lc);
        }
        child = node; node += cnt; cnt >>= 1; --lc;
    }

    root_kernel<<<B_, 128, 0, stream>>>(h, W_out, b_out, (float*)d_out);
}

// Round 7
// 294.345 us; speedup vs baseline: 1.1618x; 1.1618x over previous
//
#include <hip/hip_runtime.h>
#include <math.h>

// ---- Problem constants ----
#define B_    128
#define L_    512
#define H_    128
#define NPT_  1023
#define N_    (B_ * NPT_)     // 130944
#define NLEAF (B_ * L_)       // 65536
#define OUT_  128
#define VOCAB 32000

typedef unsigned short ushort_t;
typedef __attribute__((ext_vector_type(8))) __bf16 bf16x8;
typedef __attribute__((ext_vector_type(4))) float f32x4;

__device__ __forceinline__ float sigmoidf_(float x) {
    return 1.0f / (1.0f + __expf(-x));
}
__device__ __forceinline__ float tanhf_(float x) {
    return 1.0f - 2.0f / (__expf(2.0f * x) + 1.0f);
}
__device__ __forceinline__ ushort_t f2bf(float f) {
    unsigned u = __float_as_uint(f);
    return (ushort_t)((u + 0x7fffu + ((u >> 16) & 1u)) >> 16);
}
__device__ __forceinline__ float bf2f(ushort_t s) {
    return __uint_as_float(((unsigned)s) << 16);
}

// =====================================================================
// Prep A: weights -> bf16, transposed.
// =====================================================================
__global__ __launch_bounds__(256)
void prep_kernel(const float* __restrict__ W_iou,
                 const float* __restrict__ U_iou,
                 const float* __restrict__ U_f_w,
                 ushort_t* __restrict__ W_iouT,     // [384][128]
                 ushort_t* __restrict__ U_catT) {   // [640][256]
    int idx = blockIdx.x * 256 + threadIdx.x;
    if (idx < 640 * 256) {
        int n = idx >> 8, k = idx & 255;
        float v = (n < 384) ? U_iou[k * 384 + n] : U_f_w[k * 256 + (n - 384)];
        U_catT[idx] = f2bf(v);
    }
    if (idx < 384 * 128) {
        int n = idx >> 7, k = idx & 127;
        W_iouT[idx] = f2bf(W_iou[k * 384 + n]);
    }
}

// =====================================================================
// Prep B: emb -> bf16.
// =====================================================================
__global__ __launch_bounds__(256)
void prep_emb(const float* __restrict__ emb, ushort_t* __restrict__ embb) {
    int idx = (blockIdx.x * 256 + threadIdx.x) * 8;
    if (idx < VOCAB * H_) {
        f32x4 f0 = *(const f32x4*)(emb + idx);
        f32x4 f1 = *(const f32x4*)(emb + idx + 4);
        union { bf16x8 v; ushort_t e[8]; } p;
        p.e[0] = f2bf(f0[0]); p.e[1] = f2bf(f0[1]);
        p.e[2] = f2bf(f0[2]); p.e[3] = f2bf(f0[3]);
        p.e[4] = f2bf(f1[0]); p.e[5] = f2bf(f1[1]);
        p.e[6] = f2bf(f1[2]); p.e[7] = f2bf(f1[3]);
        *(bf16x8*)((ushort_t*)embb + idx) = p.v;
    }
}

// =====================================================================
// Leaf (direct, no LDS/barriers): wave = gate group gg over M=32 leaves.
// A (emb rows) loaded global->VGPR; per (kt,sub) lanes (q,li) cover
// 16 rows x 64B contiguous. Tiles {gg,+8,+16} = (i,o,u).
// =====================================================================
__global__ __launch_bounds__(256, 4)
void leaf_direct(const int* __restrict__ label,
                 const ushort_t* __restrict__ embb,  // [VOCAB][128] bf16
                 const ushort_t* __restrict__ WT,    // [384][128] bf16
                 const float* __restrict__ b_iou,
                 ushort_t* __restrict__ h,
                 float* __restrict__ c) {
    const int tid  = threadIdx.x;
    const int lane = tid & 63;
    const int wave = tid >> 6;
    const int li   = lane & 15;
    const int q    = lane >> 4;
    const int q8   = q << 3;
    const int i0   = blockIdx.x * 32;
    const int gg   = blockIdx.y * 4 + wave;
    const int j    = gg * 16 + li;

    // per-lane A row base pointers (emb gather via label)
    const ushort_t* pA[2];
    #pragma unroll
    for (int s = 0; s < 2; ++s) {
        int i = i0 + s * 16 + li, b = i >> 9, pos = i & 511;
        pA[s] = embb + (size_t)label[b * NPT_ + pos] * H_;
    }

    const ushort_t* bp[3];
    #pragma unroll
    for (int t = 0; t < 3; ++t)
        bp[t] = WT + (size_t)(16 * (gg + 8 * t) + li) * 128 + q8;

    f32x4 acc[2][3];
    #pragma unroll
    for (int s = 0; s < 2; ++s)
        #pragma unroll
        for (int t = 0; t < 3; ++t) acc[s][t] = (f32x4){0.f, 0.f, 0.f, 0.f};

    #pragma unroll
    for (int kt = 0; kt < 4; ++kt) {
        bf16x8 a0 = *(const bf16x8*)(pA[0] + kt * 32 + q8);
        bf16x8 a1 = *(const bf16x8*)(pA[1] + kt * 32 + q8);
        #pragma unroll
        for (int t = 0; t < 3; ++t) {
            bf16x8 bf = *(const bf16x8*)(bp[t] + kt * 32);
            acc[0][t] = __builtin_amdgcn_mfma_f32_16x16x32_bf16(a0, bf, acc[0][t], 0, 0, 0);
            acc[1][t] = __builtin_amdgcn_mfma_f32_16x16x32_bf16(a1, bf, acc[1][t], 0, 0, 0);
        }
    }

    const float bi = b_iou[j], bo = b_iou[128 + j], bu = b_iou[256 + j];
    #pragma unroll
    for (int s = 0; s < 2; ++s) {
        #pragma unroll
        for (int r = 0; r < 4; ++r) {
            int m  = i0 + s * 16 + q * 4 + r;       // row = 4*quad + reg
            int b  = m >> 9, pos = m & 511;
            size_t gn = (size_t)(b * NPT_ + pos) * H_ + j;
            float iv = sigmoidf_(acc[s][0][r] + bi);
            float ov = sigmoidf_(acc[s][1][r] + bo);
            float uv = tanhf_(acc[s][2][r] + bu);
            float cv = iv * uv;                     // c_in = 0 at leaves
            float hv = ov * tanhf_(cv);
            c[gn] = cv;
            h[gn] = f2bf(hv);
        }
    }
}

// =====================================================================
// Level (direct, no LDS/barriers): wave = gate group gg over M=32 nodes.
// A (h_cat) loaded global->VGPR: kt<4 reads left child cols kt*32,
// kt>=4 right child cols (kt-4)*32 (side = kt>>2). Epilogue c-children
// PREFETCHED at kernel start so HBM latency hides under the K-loop.
// Tiles {gg,+8,+16,+24,+32} = (i,o,u,fl,fr): lane-local epilogue.
// =====================================================================
__global__ __launch_bounds__(256, 4)
void level_direct(const ushort_t* __restrict__ Ucat,  // [640][256] bf16
                  const float* __restrict__ b_iou,
                  const float* __restrict__ U_f_b,
                  ushort_t* __restrict__ h,
                  float* __restrict__ c,
                  int node_base, int child_base, int lc) {
    const int tid  = threadIdx.x;
    const int lane = tid & 63;
    const int wave = tid >> 6;
    const int li   = lane & 15;
    const int q    = lane >> 4;
    const int q8   = q << 3;
    const int mask = (1 << lc) - 1;
    const int i0   = blockIdx.x * 32;
    const int gg   = blockIdx.y * 4 + wave;
    const int j    = gg * 16 + li;

    // per-lane A child-row base pointers [sub][side]
    const ushort_t* pA[2][2];
    #pragma unroll
    for (int s = 0; s < 2; ++s) {
        int i = i0 + s * 16 + li, b = i >> lc, pos = i & mask;
        int gl = b * NPT_ + child_base + 2 * pos;
        pA[s][0] = h + (size_t)gl * H_;
        pA[s][1] = h + (size_t)(gl + 1) * H_;
    }

    // prefetch epilogue c-children (independent of everything below)
    float clv[2][4], crv[2][4];
    int   gnrow[2][4];
    #pragma unroll
    for (int s = 0; s < 2; ++s) {
        #pragma unroll
        for (int r = 0; r < 4; ++r) {
            int m = i0 + s * 16 + q * 4 + r;
            int b = m >> lc, pos = m & mask;
            int gl = b * NPT_ + child_base + 2 * pos;
            gnrow[s][r] = b * NPT_ + node_base + pos;
            clv[s][r] = c[(size_t)gl * H_ + j];
            crv[s][r] = c[(size_t)(gl + 1) * H_ + j];
        }
    }

    const ushort_t* bp[5];
    #pragma unroll
    for (int t = 0; t < 5; ++t)
        bp[t] = Ucat + (size_t)(16 * (gg + 8 * t) + li) * 256 + q8;

    f32x4 acc[2][5];
    #pragma unroll
    for (int s = 0; s < 2; ++s)
        #pragma unroll
        for (int t = 0; t < 5; ++t) acc[s][t] = (f32x4){0.f, 0.f, 0.f, 0.f};

    #pragma unroll
    for (int kt = 0; kt < 8; ++kt) {
        const int side = kt >> 2;
        const int ko   = (kt & 3) * 32 + q8;
        bf16x8 a0 = *(const bf16x8*)(pA[0][side] + ko);
        bf16x8 a1 = *(const bf16x8*)(pA[1][side] + ko);
        #pragma unroll
        for (int t = 0; t < 5; ++t) {
            bf16x8 bf = *(const bf16x8*)(bp[t] + kt * 32);
            acc[0][t] = __builtin_amdgcn_mfma_f32_16x16x32_bf16(a0, bf, acc[0][t], 0, 0, 0);
            acc[1][t] = __builtin_amdgcn_mfma_f32_16x16x32_bf16(a1, bf, acc[1][t], 0, 0, 0);
        }
    }

    const float bi  = b_iou[j], bo = b_iou[128 + j], bu = b_iou[256 + j];
    const float bfl = U_f_b[j], bfr = U_f_b[128 + j];
    #pragma unroll
    for (int s = 0; s < 2; ++s) {
        #pragma unroll
        for (int r = 0; r < 4; ++r) {
            size_t gn = (size_t)gnrow[s][r] * H_ + j;
            float iv = sigmoidf_(acc[s][0][r] + bi);
            float ov = sigmoidf_(acc[s][1][r] + bo);
            float uv = tanhf_(acc[s][2][r] + bu);
            float fl = sigmoidf_(acc[s][3][r] + bfl);
            float fr = sigmoidf_(acc[s][4][r] + bfr);
            float cv = iv * uv + fl * clv[s][r] + fr * crv[s][r];
            float hv = ov * tanhf_(cv);
            c[gn] = cv;
            h[gn] = f2bf(hv);
        }
    }
}

// =====================================================================
// Root: logits + log_softmax.
// =====================================================================
__global__ __launch_bounds__(128)
void root_kernel(const ushort_t* __restrict__ h,
                 const float* __restrict__ W_out,
                 const float* __restrict__ b_out,
                 float* __restrict__ out) {
    __shared__ float e[H_];
    __shared__ float red[128];
    const int j = threadIdx.x;
    const int b = blockIdx.x;
    const size_t g = (size_t)(b * NPT_ + (NPT_ - 1)) * H_;

    e[j] = bf2f(h[g + j]);
    __syncthreads();

    float acc = b_out[j];
    for (int k = 0; k < H_; ++k)
        acc += e[k] * W_out[k * OUT_ + j];

    red[j] = acc; __syncthreads();
    #pragma unroll
    for (int s = 64; s > 0; s >>= 1) {
        if (j < s) red[j] = fmaxf(red[j], red[j + s]);
        __syncthreads();
    }
    float mx = red[0]; __syncthreads();

    red[j] = expf(acc - mx); __syncthreads();
    #pragma unroll
    for (int s = 64; s > 0; s >>= 1) {
        if (j < s) red[j] += red[j + s];
        __syncthreads();
    }
    float lse = logf(red[0]);

    out[b * OUT_ + j] = acc - mx - lse;
}

// =====================================================================
extern "C" void kernel_launch(void* const* d_in, const int* in_sizes, int n_in,
                              void* d_out, int out_size, void* d_ws, size_t ws_size,
                              hipStream_t stream) {
    const int*   label = (const int*)d_in[0];
    const float* emb   = (const float*)d_in[1];
    const float* W_iou = (const float*)d_in[2];
    const float* U_iou = (const float*)d_in[3];
    const float* b_iou = (const float*)d_in[4];
    const float* U_f_w = (const float*)d_in[5];
    const float* U_f_b = (const float*)d_in[6];
    const float* W_out = (const float*)d_in[7];
    const float* b_out = (const float*)d_in[8];

    float*    c    = (float*)d_ws;
    ushort_t* h    = (ushort_t*)(c + (size_t)N_ * H_);
    ushort_t* Ucat = h + (size_t)N_ * H_;
    ushort_t* WT   = Ucat + 640 * 256;
    ushort_t* embb = WT + 384 * 128;

    prep_kernel<<<640, 256, 0, stream>>>(W_iou, U_iou, U_f_w, WT, Ucat);
    prep_emb<<<(VOCAB * H_ / 8 + 255) / 256, 256, 0, stream>>>(emb, embb);

    leaf_direct<<<dim3(NLEAF / 32, 2), 256, 0, stream>>>(label, embb, WT, b_iou, h, c);

    int child = 0, node = 512, cnt = 256, lc = 8;
    for (int lvl = 0; lvl < 9; ++lvl) {
        level_direct<<<dim3((B_ * cnt) / 32, 2), 256, 0, stream>>>(
            Ucat, b_iou, U_f_b, h, c, node, child, lc);
        child = node; node += cnt; cnt >>= 1; --lc;
    }

    root_kernel<<<B_, 128, 0, stream>>>(h, W_out, b_out, (float*)d_out);
}

// Round 8
// 241.807 us; speedup vs baseline: 1.4142x; 1.2173x over previous
//
#include <hip/hip_runtime.h>
#include <math.h>

// ---- Problem constants ----
#define B_    128
#define L_    512
#define H_    128
#define NPT_  1023
#define N_    (B_ * NPT_)     // 130944
#define NLEAF (B_ * L_)       // 65536
#define OUT_  128
#define VOCAB 32000

typedef unsigned short ushort_t;
typedef __attribute__((ext_vector_type(8))) __bf16 bf16x8;
typedef __attribute__((ext_vector_type(4))) float f32x4;

__device__ __forceinline__ float sigmoidf_(float x) {
    return 1.0f / (1.0f + __expf(-x));
}
__device__ __forceinline__ float tanhf_(float x) {
    return 1.0f - 2.0f / (__expf(2.0f * x) + 1.0f);
}
__device__ __forceinline__ ushort_t f2bf(float f) {
    unsigned u = __float_as_uint(f);
    return (ushort_t)((u + 0x7fffu + ((u >> 16) & 1u)) >> 16);
}
__device__ __forceinline__ float bf2f(ushort_t s) {
    return __uint_as_float(((unsigned)s) << 16);
}

// =====================================================================
// Prep A: weights -> bf16, transposed.
// =====================================================================
__global__ __launch_bounds__(256)
void prep_kernel(const float* __restrict__ W_iou,
                 const float* __restrict__ U_iou,
                 const float* __restrict__ U_f_w,
                 ushort_t* __restrict__ W_iouT,     // [384][128]
                 ushort_t* __restrict__ U_catT) {   // [640][256]
    int idx = blockIdx.x * 256 + threadIdx.x;
    if (idx < 640 * 256) {
        int n = idx >> 8, k = idx & 255;
        float v = (n < 384) ? U_iou[k * 384 + n] : U_f_w[k * 256 + (n - 384)];
        U_catT[idx] = f2bf(v);
    }
    if (idx < 384 * 128) {
        int n = idx >> 7, k = idx & 127;
        W_iouT[idx] = f2bf(W_iou[k * 384 + n]);
    }
}

// =====================================================================
// Prep B: emb -> bf16.
// =====================================================================
__global__ __launch_bounds__(256)
void prep_emb(const float* __restrict__ emb, ushort_t* __restrict__ embb) {
    int idx = (blockIdx.x * 256 + threadIdx.x) * 8;
    if (idx < VOCAB * H_) {
        f32x4 f0 = *(const f32x4*)(emb + idx);
        f32x4 f1 = *(const f32x4*)(emb + idx + 4);
        union { bf16x8 v; ushort_t e[8]; } p;
        p.e[0] = f2bf(f0[0]); p.e[1] = f2bf(f0[1]);
        p.e[2] = f2bf(f0[2]); p.e[3] = f2bf(f0[3]);
        p.e[4] = f2bf(f1[0]); p.e[5] = f2bf(f1[1]);
        p.e[6] = f2bf(f1[2]); p.e[7] = f2bf(f1[3]);
        *(bf16x8*)((ushort_t*)embb + idx) = p.v;
    }
}

// =====================================================================
// Leaf v3 (B register-resident): wave = gate group gg; B slice
// (3 tiles x 4 kt = 12 frags, 48 VGPR) loaded ONCE; grid-stride loop
// over M-tiles of 16 leaves (acc[3]=12 AGPR, A=8 frags/tile).
// Tiles {gg,+8,+16} = (i,o,u): lane-local cell epilogue.
// =====================================================================
__global__ __launch_bounds__(256, 4)
void leaf_v3(const int* __restrict__ label,
             const ushort_t* __restrict__ embb,  // [VOCAB][128] bf16
             const ushort_t* __restrict__ WT,    // [384][128] bf16
             const float* __restrict__ b_iou,
             ushort_t* __restrict__ h,
             float* __restrict__ c,
             int ntiles, int stripes) {
    const int tid  = threadIdx.x;
    const int lane = tid & 63;
    const int wave = tid >> 6;
    const int li   = lane & 15;
    const int q    = lane >> 4;
    const int q8   = q << 3;
    const int gg   = blockIdx.y * 4 + wave;
    const int j    = gg * 16 + li;

    // B once: 3 tiles x 4 kt
    bf16x8 Bf[3][4];
    #pragma unroll
    for (int t = 0; t < 3; ++t) {
        const ushort_t* bp = WT + (size_t)(16 * (gg + 8 * t) + li) * 128 + q8;
        #pragma unroll
        for (int kt = 0; kt < 4; ++kt) Bf[t][kt] = *(const bf16x8*)(bp + kt * 32);
    }

    const float bi = b_iou[j], bo = b_iou[128 + j], bu = b_iou[256 + j];

    for (int tile = blockIdx.x; tile < ntiles; tile += stripes) {
        const int i0 = tile * 16;
        // A: 16 emb rows (one per li), gathered via label
        int ia = i0 + li, ba = ia >> 9, pa = ia & 511;
        const ushort_t* pA = embb + (size_t)label[ba * NPT_ + pa] * H_;
        bf16x8 a[4];
        #pragma unroll
        for (int kt = 0; kt < 4; ++kt) a[kt] = *(const bf16x8*)(pA + kt * 32 + q8);

        f32x4 acc[3];
        #pragma unroll
        for (int t = 0; t < 3; ++t) acc[t] = (f32x4){0.f, 0.f, 0.f, 0.f};
        #pragma unroll
        for (int kt = 0; kt < 4; ++kt)
            #pragma unroll
            for (int t = 0; t < 3; ++t)
                acc[t] = __builtin_amdgcn_mfma_f32_16x16x32_bf16(a[kt], Bf[t][kt], acc[t], 0, 0, 0);

        #pragma unroll
        for (int r = 0; r < 4; ++r) {
            int m  = i0 + q * 4 + r;                // row = 4*quad + reg
            int b  = m >> 9, pos = m & 511;
            size_t gn = (size_t)(b * NPT_ + pos) * H_ + j;
            float iv = sigmoidf_(acc[0][r] + bi);
            float ov = sigmoidf_(acc[1][r] + bo);
            float uv = tanhf_(acc[2][r] + bu);
            float cv = iv * uv;                     // c_in = 0 at leaves
            float hv = ov * tanhf_(cv);
            c[gn] = cv;
            h[gn] = f2bf(hv);
        }
    }
}

// =====================================================================
// Level v3 (B register-resident): wave = gate group gg; B slice
// (5 tiles x 8 kt = 40 frags, 160 VGPR) loaded ONCE; grid-stride loop
// over M-tiles of 16 nodes (acc[5]=20 AGPR, A=8 frags + 8 c-vals/tile).
// Tiles {gg,+8,+16,+24,+32} = (i,o,u,fl,fr): lane-local epilogue.
// =====================================================================
__global__ __launch_bounds__(256, 2)
void level_v3(const ushort_t* __restrict__ Ucat,  // [640][256] bf16
              const float* __restrict__ b_iou,
              const float* __restrict__ U_f_b,
              ushort_t* __restrict__ h,
              float* __restrict__ c,
              int node_base, int child_base, int lc,
              int ntiles, int stripes) {
    const int tid  = threadIdx.x;
    const int lane = tid & 63;
    const int wave = tid >> 6;
    const int li   = lane & 15;
    const int q    = lane >> 4;
    const int q8   = q << 3;
    const int mask = (1 << lc) - 1;
    const int gg   = blockIdx.y * 4 + wave;
    const int j    = gg * 16 + li;

    // B once: 5 tiles x 8 kt (stays in registers across the M-loop)
    bf16x8 Bf[5][8];
    #pragma unroll
    for (int t = 0; t < 5; ++t) {
        const ushort_t* bp = Ucat + (size_t)(16 * (gg + 8 * t) + li) * 256 + q8;
        #pragma unroll
        for (int kt = 0; kt < 8; ++kt) Bf[t][kt] = *(const bf16x8*)(bp + kt * 32);
    }

    const float bi  = b_iou[j], bo = b_iou[128 + j], bu = b_iou[256 + j];
    const float bfl = U_f_b[j], bfr = U_f_b[128 + j];

    for (int tile = blockIdx.x; tile < ntiles; tile += stripes) {
        const int i0 = tile * 16;

        // epilogue c-children prefetch (independent; hides under K-loop)
        float clv[4], crv[4];
        int   gnrow[4];
        #pragma unroll
        for (int r = 0; r < 4; ++r) {
            int m = i0 + q * 4 + r;
            int b = m >> lc, pos = m & mask;
            int gl = b * NPT_ + child_base + 2 * pos;
            gnrow[r] = b * NPT_ + node_base + pos;
            clv[r] = c[(size_t)gl * H_ + j];
            crv[r] = c[(size_t)(gl + 1) * H_ + j];
        }

        // A: 16 h_cat rows (one per li); kt<4 left child, kt>=4 right
        int ia = i0 + li, ba = ia >> lc, pa = ia & mask;
        int gl0 = ba * NPT_ + child_base + 2 * pa;
        const ushort_t* pl = h + (size_t)gl0 * H_;
        const ushort_t* pr = h + (size_t)(gl0 + 1) * H_;
        bf16x8 a[8];
        #pragma unroll
        for (int kt = 0; kt < 8; ++kt) {
            const ushort_t* p = (kt < 4) ? pl : pr;
            a[kt] = *(const bf16x8*)(p + (kt & 3) * 32 + q8);
        }

        f32x4 acc[5];
        #pragma unroll
        for (int t = 0; t < 5; ++t) acc[t] = (f32x4){0.f, 0.f, 0.f, 0.f};
        #pragma unroll
        for (int kt = 0; kt < 8; ++kt)
            #pragma unroll
            for (int t = 0; t < 5; ++t)
                acc[t] = __builtin_amdgcn_mfma_f32_16x16x32_bf16(a[kt], Bf[t][kt], acc[t], 0, 0, 0);

        #pragma unroll
        for (int r = 0; r < 4; ++r) {
            size_t gn = (size_t)gnrow[r] * H_ + j;
            float iv = sigmoidf_(acc[0][r] + bi);
            float ov = sigmoidf_(acc[1][r] + bo);
            float uv = tanhf_(acc[2][r] + bu);
            float fl = sigmoidf_(acc[3][r] + bfl);
            float fr = sigmoidf_(acc[4][r] + bfr);
            float cv = iv * uv + fl * clv[r] + fr * crv[r];
            float hv = ov * tanhf_(cv);
            c[gn] = cv;
            h[gn] = f2bf(hv);
        }
    }
}

// =====================================================================
// Root: logits + log_softmax.
// =====================================================================
__global__ __launch_bounds__(128)
void root_kernel(const ushort_t* __restrict__ h,
                 const float* __restrict__ W_out,
                 const float* __restrict__ b_out,
                 float* __restrict__ out) {
    __shared__ float e[H_];
    __shared__ float red[128];
    const int j = threadIdx.x;
    const int b = blockIdx.x;
    const size_t g = (size_t)(b * NPT_ + (NPT_ - 1)) * H_;

    e[j] = bf2f(h[g + j]);
    __syncthreads();

    float acc = b_out[j];
    for (int k = 0; k < H_; ++k)
        acc += e[k] * W_out[k * OUT_ + j];

    red[j] = acc; __syncthreads();
    #pragma unroll
    for (int s = 64; s > 0; s >>= 1) {
        if (j < s) red[j] = fmaxf(red[j], red[j + s]);
        __syncthreads();
    }
    float mx = red[0]; __syncthreads();

    red[j] = expf(acc - mx); __syncthreads();
    #pragma unroll
    for (int s = 64; s > 0; s >>= 1) {
        if (j < s) red[j] += red[j + s];
        __syncthreads();
    }
    float lse = logf(red[0]);

    out[b * OUT_ + j] = acc - mx - lse;
}

// =====================================================================
extern "C" void kernel_launch(void* const* d_in, const int* in_sizes, int n_in,
                              void* d_out, int out_size, void* d_ws, size_t ws_size,
                              hipStream_t stream) {
    const int*   label = (const int*)d_in[0];
    const float* emb   = (const float*)d_in[1];
    const float* W_iou = (const float*)d_in[2];
    const float* U_iou = (const float*)d_in[3];
    const float* b_iou = (const float*)d_in[4];
    const float* U_f_w = (const float*)d_in[5];
    const float* U_f_b = (const float*)d_in[6];
    const float* W_out = (const float*)d_in[7];
    const float* b_out = (const float*)d_in[8];

    float*    c    = (float*)d_ws;
    ushort_t* h    = (ushort_t*)(c + (size_t)N_ * H_);
    ushort_t* Ucat = h + (size_t)N_ * H_;
    ushort_t* WT   = Ucat + 640 * 256;
    ushort_t* embb = WT + 384 * 128;

    prep_kernel<<<640, 256, 0, stream>>>(W_iou, U_iou, U_f_w, WT, Ucat);
    prep_emb<<<(VOCAB * H_ / 8 + 255) / 256, 256, 0, stream>>>(emb, embb);

    {   // leaf: 4096 M-tiles of 16; 512 stripes x 2 group-halves
        int ntiles = NLEAF / 16, stripes = 512;
        leaf_v3<<<dim3(stripes, 2), 256, 0, stream>>>(
            label, embb, WT, b_iou, h, c, ntiles, stripes);
    }

    int child = 0, node = 512, cnt = 256, lc = 8;
    for (int lvl = 0; lvl < 9; ++lvl) {
        int rows = B_ * cnt;
        int ntiles  = rows / 16;
        int stripes = ntiles < 256 ? ntiles : 256;
        level_v3<<<dim3(stripes, 2), 256, 0, stream>>>(
            Ucat, b_iou, U_f_b, h, c, node, child, lc, ntiles, stripes);
        child = node; node += cnt; cnt >>= 1; --lc;
    }

    root_kernel<<<B_, 128, 0, stream>>>(h, W_out, b_out, (float*)d_out);
}